// Round 17
// baseline (140.120 us; speedup 1.0000x reference)
//
#include <hip/hip_runtime.h>
#include <stdint.h>

typedef unsigned short u16;
typedef __attribute__((ext_vector_type(8))) short short8;
typedef __attribute__((ext_vector_type(4))) float f32x4;
typedef __attribute__((ext_vector_type(16))) float f32x16;

typedef __attribute__((address_space(1))) void as1_void;
typedef __attribute__((address_space(3))) void as3_void;

__device__ inline u16 f2bf(float x) {
  uint32_t u = __float_as_uint(x);
  return (u16)((u + 0x7fffu + ((u >> 16) & 1u)) >> 16);
}

__device__ inline void gload16(const void* g, void* l) {
  __builtin_amdgcn_global_load_lds((as1_void*)g, (as3_void*)l, 16, 0, 0);
}

__device__ inline uint32_t cvtpk(float lo, float hi) {
  uint32_t d;
  asm("v_cvt_pk_bf16_f32 %0, %1, %2" : "=v"(d) : "v"(lo), "v"(hi));
  return d;
}

// NOTE: only safe when a and b hold DIFFERENT values (distinct registers).
// Never call with two copies of the same value — regalloc may coalesce them
// into one VGPR and the swap becomes a self-swap (R3/R4/R8 failure cause).
__device__ inline void plswap(uint32_t& a, uint32_t& b) {
  asm("v_permlane32_swap_b32 %0, %1" : "+v"(a), "+v"(b));
}

__device__ inline float fexp2(float x) {
  float r;
  asm("v_exp_f32 %0, %1" : "=v"(r) : "v"(x));
  return r;
}

// ---------------- f32 -> bf16 conversion, weights only (4 x 512x512) --------
__global__ __launch_bounds__(256) void cvt_w(const float* __restrict__ Wq,
                                             const float* __restrict__ Wk,
                                             const float* __restrict__ Wv,
                                             const float* __restrict__ Wo,
                                             u16* __restrict__ wall) {
  const int widx = blockIdx.x >> 8;
  const float* in = (widx == 0) ? Wq : (widx == 1) ? Wk : (widx == 2) ? Wv : Wo;
  u16* out = wall + (size_t)widx * 262144;
  int i = (blockIdx.x & 255) * 256 + threadIdx.x;
  float4 v = ((const float4*)in)[i];
  ushort4 o;
  o.x = f2bf(v.x); o.y = f2bf(v.y); o.z = f2bf(v.z); o.w = f2bf(v.w);
  ((ushort4*)out)[i] = o;
}

// ---------------- fused QKV projection GEMM, f32-A reg-staged ---------------
// Tile 64x128, 4 waves, BK=64, dbuf. W staged via gload16 (bf16); A staged
// from f32 q/kv: reg-load -> cvt_pk_bf16 -> ds_write producing the SAME
// swizzled chunk layout (chunk t = row tid>>3, k-chunk (tid&7)^(row&7)).
// grid (128,4,3): z=0 Q (prescale), z=1 K, z=2 V (transposed out).
__global__ __launch_bounds__(256) void gemm_qkv(const float* __restrict__ qf,
                                                const float* __restrict__ kvf,
                                                const u16* __restrict__ wq,
                                                const u16* __restrict__ wk,
                                                const u16* __restrict__ wv,
                                                const float* __restrict__ bq,
                                                const float* __restrict__ bk,
                                                const float* __restrict__ bv,
                                                u16* __restrict__ Qh,
                                                u16* __restrict__ Kh,
                                                u16* __restrict__ Vt, float qscale) {
  __shared__ __align__(16) char smem[49152];
  const int z = blockIdx.z;
  const float* Af = (z == 0) ? qf : kvf;
  const u16* W = (z == 0) ? wq : (z == 1) ? wk : wv;
  const float* bias = (z == 0) ? bq : (z == 1) ? bk : bv;
  const float prescale = (z == 0) ? qscale : 1.0f;
  u16* Cout = (z == 0) ? Qh : (z == 1) ? Kh : Vt;

  const int tid = threadIdx.x;
  const int lane = tid & 63;
  const int wv_ = tid >> 6;
  const int c = lane & 15;
  const int g = lane >> 4;
  const int wr = wv_ >> 1, wc = wv_ & 1;
  const int m0 = blockIdx.x * 64;
  const int n0 = blockIdx.y * 128;

  const int r0 = tid >> 3, cc = tid & 7;
  const int u0 = cc ^ (r0 & 7);
  const float* srcAf = Af + (size_t)(m0 + r0) * 512 + u0 * 8;
  const u16* srcW0 = W + (size_t)(n0 + r0) * 512 + u0 * 8;

#define QKV_W_STAGE(BUF, KK)                             \
  {                                                      \
    char* ab_ = (char*)smem + (BUF)*24576 + wv_ * 1024;  \
    gload16(srcW0 + (KK), ab_ + 8192);                   \
    gload16(srcW0 + (KK) + 16384, ab_ + 12288);          \
    gload16(srcW0 + (KK) + 32768, ab_ + 16384);          \
    gload16(srcW0 + (KK) + 49152, ab_ + 20480);          \
  }

#define QKV_A_WRITE(BUF)                                          \
  {                                                               \
    union { uint32_t u[4]; int4 v; } w0_, w1_;                    \
    w0_.u[0] = cvtpk(a0.x, a0.y); w0_.u[1] = cvtpk(a0.z, a0.w);   \
    w0_.u[2] = cvtpk(a1.x, a1.y); w0_.u[3] = cvtpk(a1.z, a1.w);   \
    w1_.u[0] = cvtpk(a2.x, a2.y); w1_.u[1] = cvtpk(a2.z, a2.w);   \
    w1_.u[2] = cvtpk(a3.x, a3.y); w1_.u[3] = cvtpk(a3.z, a3.w);   \
    char* db_ = (char*)smem + (BUF)*24576;                        \
    *(int4*)(db_ + tid * 16) = w0_.v;                             \
    *(int4*)(db_ + 4096 + tid * 16) = w1_.v;                      \
  }

  f32x4 acc[2][4];
#pragma unroll
  for (int i = 0; i < 2; i++)
#pragma unroll
    for (int j = 0; j < 4; j++) acc[i][j] = (f32x4){0.f, 0.f, 0.f, 0.f};

  // prologue: stage K-step 0 into buf 0
  {
    QKV_W_STAGE(0, 0)
    float4 a0 = *(const float4*)(srcAf);
    float4 a1 = *(const float4*)(srcAf + 4);
    float4 a2 = *(const float4*)(srcAf + 16384);   // row +32 (32*512)
    float4 a3 = *(const float4*)(srcAf + 16388);
    QKV_A_WRITE(0)
  }
  __syncthreads();
  int cur = 0;
  const int swa = c & 7;
  for (int it = 0; it < 8; ++it) {
    float4 a0, a1, a2, a3;
    if (it < 7) {
      const int kn = (it + 1) * 64;
      QKV_W_STAGE(cur ^ 1, kn)
      a0 = *(const float4*)(srcAf + kn);
      a1 = *(const float4*)(srcAf + kn + 4);
      a2 = *(const float4*)(srcAf + kn + 16384);
      a3 = *(const float4*)(srcAf + kn + 16388);
    }
    const u16* Ab = (const u16*)((char*)smem + cur * 24576);
    const u16* Wb = Ab + 4096;
#pragma unroll
    for (int kd = 0; kd < 2; kd++) {
      short8 af[2], wf[4];
#pragma unroll
      for (int ai = 0; ai < 2; ai++)
        af[ai] = *(const short8*)&Ab[(wr * 32 + ai * 16 + c) * 64 + (((kd * 4 + g) ^ swa) << 3)];
#pragma unroll
      for (int bj = 0; bj < 4; bj++)
        wf[bj] = *(const short8*)&Wb[(wc * 64 + bj * 16 + c) * 64 + (((kd * 4 + g) ^ swa) << 3)];
#pragma unroll
      for (int ai = 0; ai < 2; ai++)
#pragma unroll
        for (int bj = 0; bj < 4; bj++)
          acc[ai][bj] = __builtin_amdgcn_mfma_f32_16x16x32_bf16(af[ai], wf[bj], acc[ai][bj], 0, 0, 0);
    }
    if (it < 7) QKV_A_WRITE(cur ^ 1)
    __syncthreads();
    cur ^= 1;
  }

#pragma unroll
  for (int ai = 0; ai < 2; ai++)
#pragma unroll
    for (int bj = 0; bj < 4; bj++)
#pragma unroll
      for (int r = 0; r < 4; r++) {
        int m = m0 + wr * 32 + ai * 16 + g * 4 + r;
        int n = n0 + wc * 64 + bj * 16 + c;
        float v = (acc[ai][bj][r] + bias[n]) * prescale;
        int b = m >> 12, s = m & 4095;
        int h = n >> 6, d = n & 63;
        size_t idx;
        if (z < 2)
          idx = ((size_t)(b * 8 + h) * 4096 + s) * 64 + d;
        else
          idx = ((size_t)(b * 8 + h) * 64 + d) * 4096 + s;
        Cout[idx] = f2bf(v);
      }
}

// ---------------- output projection GEMM with fused attn-combine ------------
// A[m,k] = (Op0[m,k] + Op1[m,k]) / l[m, k>>6], staged from the two f32 partial
// buffers with the per-(row,head) normalization applied during staging (BK=64
// spans exactly one head block, so 1/l is a per-step scalar per row). W via
// gload16. Epilogue unchanged (f32 out + bias).
__global__ __launch_bounds__(256) void gemm_out(const float* __restrict__ Op,
                                                const float* __restrict__ Lw,
                                                const u16* __restrict__ W,
                                                const float* __restrict__ bias,
                                                float* __restrict__ Cout) {
  __shared__ __align__(16) char smem[49152];
  const int tid = threadIdx.x;
  const int lane = tid & 63;
  const int wv_ = tid >> 6;
  const int c = lane & 15;
  const int g = lane >> 4;
  const int wr = wv_ >> 1, wc = wv_ & 1;
  const int m0 = blockIdx.x * 64;
  const int n0 = blockIdx.y * 128;

  const int r0 = tid >> 3, cc = tid & 7;
  const int u0 = cc ^ (r0 & 7);
  const u16* srcW0 = W + (size_t)(n0 + r0) * 512 + u0 * 8;

  const int b_blk = m0 >> 12;
  const int sb = (m0 & 4095) + r0;
  // half-0 base for (head hh=0, row sb, elems u0*8..): + hh*262144 per K-step
  const float* srcO0 = Op + ((size_t)(b_blk * 8) * 4096 + sb) * 64 + u0 * 8;
  const float* lw0 = Lw + (size_t)(b_blk * 8) * 4096 + sb;

#define OUT_W_STAGE(BUF, KK)                             \
  {                                                      \
    char* ab_ = (char*)smem + (BUF)*24576 + wv_ * 1024;  \
    gload16(srcW0 + (KK), ab_ + 8192);                   \
    gload16(srcW0 + (KK) + 16384, ab_ + 12288);          \
    gload16(srcW0 + (KK) + 32768, ab_ + 16384);          \
    gload16(srcW0 + (KK) + 49152, ab_ + 20480);          \
  }

#define OUT_A_LOAD(HH)                                              \
  {                                                                 \
    const float* p_ = srcO0 + (size_t)(HH)*262144;                  \
    x0 = *(const float4*)(p_);                                      \
    x1 = *(const float4*)(p_ + 4);                                  \
    x2 = *(const float4*)(p_ + 2048);   /* row +32 */               \
    x3 = *(const float4*)(p_ + 2052);                               \
    y0 = *(const float4*)(p_ + 4194304);                            \
    y1 = *(const float4*)(p_ + 4194308);                            \
    y2 = *(const float4*)(p_ + 4196352);                            \
    y3 = *(const float4*)(p_ + 4196356);                            \
    float la0 = lw0[(size_t)(HH)*4096];                             \
    float lb0 = lw0[65536 + (size_t)(HH)*4096];                     \
    float la1 = lw0[(size_t)(HH)*4096 + 32];                        \
    float lb1 = lw0[65536 + (size_t)(HH)*4096 + 32];                \
    il0 = 1.0f / (la0 + lb0);                                       \
    il1 = 1.0f / (la1 + lb1);                                       \
  }

#define OUT_A_WRITE(BUF)                                                        \
  {                                                                             \
    union { uint32_t u[4]; int4 v; } w0_, w1_;                                  \
    w0_.u[0] = cvtpk((x0.x + y0.x) * il0, (x0.y + y0.y) * il0);                 \
    w0_.u[1] = cvtpk((x0.z + y0.z) * il0, (x0.w + y0.w) * il0);                 \
    w0_.u[2] = cvtpk((x1.x + y1.x) * il0, (x1.y + y1.y) * il0);                 \
    w0_.u[3] = cvtpk((x1.z + y1.z) * il0, (x1.w + y1.w) * il0);                 \
    w1_.u[0] = cvtpk((x2.x + y2.x) * il1, (x2.y + y2.y) * il1);                 \
    w1_.u[1] = cvtpk((x2.z + y2.z) * il1, (x2.w + y2.w) * il1);                 \
    w1_.u[2] = cvtpk((x3.x + y3.x) * il1, (x3.y + y3.y) * il1);                 \
    w1_.u[3] = cvtpk((x3.z + y3.z) * il1, (x3.w + y3.w) * il1);                 \
    char* db_ = (char*)smem + (BUF)*24576;                                      \
    *(int4*)(db_ + tid * 16) = w0_.v;                                           \
    *(int4*)(db_ + 4096 + tid * 16) = w1_.v;                                    \
  }

  f32x4 acc[2][4];
#pragma unroll
  for (int i = 0; i < 2; i++)
#pragma unroll
    for (int j = 0; j < 4; j++) acc[i][j] = (f32x4){0.f, 0.f, 0.f, 0.f};

  {
    float4 x0, x1, x2, x3, y0, y1, y2, y3;
    float il0, il1;
    OUT_W_STAGE(0, 0)
    OUT_A_LOAD(0)
    OUT_A_WRITE(0)
  }
  __syncthreads();
  int cur = 0;
  const int swa = c & 7;
  for (int it = 0; it < 8; ++it) {
    float4 x0, x1, x2, x3, y0, y1, y2, y3;
    float il0, il1;
    if (it < 7) {
      OUT_W_STAGE(cur ^ 1, (it + 1) * 64)
      OUT_A_LOAD(it + 1)
    }
    const u16* Ab = (const u16*)((char*)smem + cur * 24576);
    const u16* Wb = Ab + 4096;
#pragma unroll
    for (int kd = 0; kd < 2; kd++) {
      short8 af[2], wf[4];
#pragma unroll
      for (int ai = 0; ai < 2; ai++)
        af[ai] = *(const short8*)&Ab[(wr * 32 + ai * 16 + c) * 64 + (((kd * 4 + g) ^ swa) << 3)];
#pragma unroll
      for (int bj = 0; bj < 4; bj++)
        wf[bj] = *(const short8*)&Wb[(wc * 64 + bj * 16 + c) * 64 + (((kd * 4 + g) ^ swa) << 3)];
#pragma unroll
      for (int ai = 0; ai < 2; ai++)
#pragma unroll
        for (int bj = 0; bj < 4; bj++)
          acc[ai][bj] = __builtin_amdgcn_mfma_f32_16x16x32_bf16(af[ai], wf[bj], acc[ai][bj], 0, 0, 0);
    }
    if (it < 7) OUT_A_WRITE(cur ^ 1)
    __syncthreads();
    cur ^= 1;
  }

#pragma unroll
  for (int ai = 0; ai < 2; ai++)
#pragma unroll
    for (int bj = 0; bj < 4; bj++)
#pragma unroll
      for (int r = 0; r < 4; r++) {
        int m = m0 + wr * 32 + ai * 16 + g * 4 + r;
        int n = n0 + wc * 64 + bj * 16 + c;
        Cout[(size_t)m * 512 + n] = acc[ai][bj][r] + bias[n];
      }
}

// ---------------- Flash attention: PV-lagged software pipeline (R16) --------
__global__ __launch_bounds__(256) void attn_split(const u16* __restrict__ Qh,
                                                  const u16* __restrict__ Kh,
                                                  const u16* __restrict__ Vt,
                                                  float* __restrict__ Op,
                                                  float* __restrict__ Lw) {
  __shared__ __align__(16) char smem[32768];
  const int tid = threadIdx.x;
  const int lane = tid & 63;
  const int w = tid >> 6;
  const int c5 = lane & 31;
  const int h = lane >> 5;
  const int bid = (blockIdx.x & 7) * 128 + (blockIdx.x >> 3);  // bijective XCD swizzle
  const int half = bid & 1;
  const int qt = (bid >> 1) & 31;
  const int bh = bid >> 6;
  const int q0 = qt * 128 + w * 32;
  const u16* Qb = Qh + (size_t)bh * 262144;
  const u16* Kb = Kh + (size_t)bh * 262144 + (size_t)half * 2048 * 64;
  const u16* Vb = Vt + (size_t)bh * 262144 + half * 2048;

  // Q B-frag (pre-scaled by log2e/8 in projection)
  short8 qf[4];
#pragma unroll
  for (int kd = 0; kd < 4; kd++)
    qf[kd] = *(const short8*)(Qb + (size_t)(q0 + c5) * 64 + kd * 16 + h * 8);

  f32x16 accO[2];
#pragma unroll
  for (int i = 0; i < 16; i++) { accO[0][i] = 0.f; accO[1][i] = 0.f; }
  float l_loc = 0.f;

  // gload_lds sources (verified R10): thread t -> LDS row r=t>>4 pos p=t&15
  const int r = tid >> 4, p = tid & 15;
  const int x = p ^ r;
  const int gb = x >> 3, ge = x & 7;
  const u16* srcKA = Kb + (size_t)(r + 32 * gb) * 64 + ge * 8;
  const u16* srcKB = Kb + (size_t)(16 + r + 32 * gb) * 64 + ge * 8;
  const u16* srcVA = Vb + (size_t)(r + 32 * gb) * 4096 + ge * 8;
  const u16* srcVB = Vb + (size_t)(16 + r + 32 * gb) * 4096 + ge * 8;

#define ATTN_STAGE(BUF, T)                                \
  {                                                       \
    char* b_ = (char*)smem + (BUF)*16384 + w * 1024;      \
    gload16(srcKA + (size_t)(T)*4096, b_);                \
    gload16(srcKB + (size_t)(T)*4096, b_ + 4096);         \
    gload16(srcVA + (T)*64, b_ + 8192);                   \
    gload16(srcVB + (T)*64, b_ + 12288);                  \
  }

  ATTN_STAGE(0, 0)
  __syncthreads();
  const int swz = c5 & 15;
  const int rowb = c5 * 128;

  short8 pa_prev[4];   // P-frags of tile t-1 (carried)
  short8 vf_prev[8];   // V-frags of tile t-1 (carried)

  for (int t = 0; t < 32; ++t) {
    const int cur = t & 1;
    if (t < 31) ATTN_STAGE(cur ^ 1, t + 1)

    const u16* Kl = (const u16*)(smem + cur * 16384);
    const u16* Vl = Kl + 4096;

    // ---- MFMA cluster: QK_t then PV_{t-1} (fills matrix pipe) ----
    f32x16 s0, s1;
#pragma unroll
    for (int i = 0; i < 16; i++) { s0[i] = 0.f; s1[i] = 0.f; }
    __builtin_amdgcn_s_setprio(1);
#pragma unroll
    for (int kd = 0; kd < 4; kd++) {
      short8 kf0 = *(const short8*)&Kl[rowb + ((((kd << 1) + h) ^ swz) << 3)];
      short8 kf1 = *(const short8*)&Kl[rowb + (((8 + (kd << 1) + h) ^ swz) << 3)];
      s0 = __builtin_amdgcn_mfma_f32_32x32x16_bf16(kf0, qf[kd], s0, 0, 0, 0);
      s1 = __builtin_amdgcn_mfma_f32_32x32x16_bf16(kf1, qf[kd], s1, 0, 0, 0);
    }
    if (t > 0) {
#pragma unroll
      for (int km = 0; km < 4; km++) {
        accO[0] = __builtin_amdgcn_mfma_f32_32x32x16_bf16(vf_prev[2 * km], pa_prev[km], accO[0], 0, 0, 0);
        accO[1] = __builtin_amdgcn_mfma_f32_32x32x16_bf16(vf_prev[2 * km + 1], pa_prev[km], accO[1], 0, 0, 0);
      }
    }
    __builtin_amdgcn_s_setprio(0);
    __builtin_amdgcn_sched_barrier(0);  // pin: MFMAs issue before softmax VALU

    // ---- softmax_t in the MFMA shadow ----
#pragma unroll
    for (int i = 0; i < 16; i++) { s0[i] = fexp2(s0[i]); s1[i] = fexp2(s1[i]); }

    float tsum0 = ((s0[0] + s1[0]) + (s0[4] + s1[4])) + ((s0[8] + s1[8]) + (s0[12] + s1[12]));
    float tsum1 = ((s0[1] + s1[1]) + (s0[5] + s1[5])) + ((s0[9] + s1[9]) + (s0[13] + s1[13]));
    float tsum2 = ((s0[2] + s1[2]) + (s0[6] + s1[6])) + ((s0[10] + s1[10]) + (s0[14] + s1[14]));
    float tsum3 = ((s0[3] + s1[3]) + (s0[7] + s1[7])) + ((s0[11] + s1[11]) + (s0[15] + s1[15]));
    l_loc += (tsum0 + tsum1) + (tsum2 + tsum3);

    uint32_t pk0[4][2], pk1[4][2];
#pragma unroll
    for (int u = 0; u < 4; u++) {
      pk0[u][0] = cvtpk(s0[4 * u], s0[4 * u + 1]);
      pk0[u][1] = cvtpk(s0[4 * u + 2], s0[4 * u + 3]);
      pk1[u][0] = cvtpk(s1[4 * u], s1[4 * u + 1]);
      pk1[u][1] = cvtpk(s1[4 * u + 2], s1[4 * u + 3]);
    }
#pragma unroll
    for (int km = 0; km < 2; km++) {
      const int uA = (km & 1) * 2, uB = uA + 1;
      uint32_t a0 = pk0[uA][0], b0 = pk0[uB][0]; plswap(a0, b0);
      uint32_t a1 = pk0[uA][1], b1 = pk0[uB][1]; plswap(a1, b1);
      union { uint32_t u[4]; short8 s; } uu;
      uu.u[0] = a0; uu.u[1] = a1; uu.u[2] = b0; uu.u[3] = b1;
      pa_prev[km] = uu.s;
    }
#pragma unroll
    for (int km = 2; km < 4; km++) {
      const int uA = (km & 1) * 2, uB = uA + 1;
      uint32_t a0 = pk1[uA][0], b0 = pk1[uB][0]; plswap(a0, b0);
      uint32_t a1 = pk1[uA][1], b1 = pk1[uB][1]; plswap(a1, b1);
      union { uint32_t u[4]; short8 s; } uu;
      uu.u[0] = a0; uu.u[1] = a1; uu.u[2] = b0; uu.u[3] = b1;
      pa_prev[km] = uu.s;
    }

    // ---- V_t frags LDS -> regs (consumed by PV at iter t+1) ----
#pragma unroll
    for (int km = 0; km < 4; km++) {
      vf_prev[2 * km]     = *(const short8*)&Vl[rowb + ((((km << 1) + h) ^ swz) << 3)];
      vf_prev[2 * km + 1] = *(const short8*)&Vl[rowb + (((8 + (km << 1) + h) ^ swz) << 3)];
    }

    __syncthreads();  // drains DMA; flips buffer
  }

  // ---- epilogue: PV_31 + deferred cross-half l reduce ----
#pragma unroll
  for (int km = 0; km < 4; km++) {
    accO[0] = __builtin_amdgcn_mfma_f32_32x32x16_bf16(vf_prev[2 * km], pa_prev[km], accO[0], 0, 0, 0);
    accO[1] = __builtin_amdgcn_mfma_f32_32x32x16_bf16(vf_prev[2 * km + 1], pa_prev[km], accO[1], 0, 0, 0);
  }
  const float l_r = l_loc + __shfl_xor(l_loc, 32);

  // ---- write f32 partials + l to workspace ----
  const size_t pbase = (size_t)(half * 16 + bh) * 4096 + q0 + c5;
  float* Opw = Op + pbase * 64;
#pragma unroll
  for (int db = 0; db < 2; db++)
#pragma unroll
    for (int rr = 0; rr < 16; rr++) {
      int d = db * 32 + 4 * h + (rr & 3) + 8 * (rr >> 2);
      Opw[d] = accO[db][rr];
    }
  if (h == 0) Lw[pbase] = l_r;
}

// ---------------- host launch ----------------
extern "C" void kernel_launch(void* const* d_in, const int* in_sizes, int n_in,
                              void* d_out, int out_size, void* d_ws, size_t ws_size,
                              hipStream_t stream) {
  const float* q  = (const float*)d_in[0];
  const float* kv = (const float*)d_in[1];
  const float* Wq = (const float*)d_in[2];
  const float* bq = (const float*)d_in[3];
  const float* Wk = (const float*)d_in[4];
  const float* bk = (const float*)d_in[5];
  const float* Wv = (const float*)d_in[6];
  const float* bv = (const float*)d_in[7];
  const float* Wo = (const float*)d_in[8];
  const float* bo = (const float*)d_in[9];

  const size_t MB = 1u << 20;
  char* ws = (char*)d_ws;
  u16* wqb = (u16*)(ws + 16 * MB);   // 4 weights contiguous: wq,wk,wv,wo
  u16* wkb = (u16*)(ws + 16 * MB + 524288);
  u16* wvb = (u16*)(ws + 17 * MB);
  u16* wob = (u16*)(ws + 17 * MB + 524288);
  u16* Qh  = (u16*)(ws + 18 * MB);   // [16][4096][64], pre-scaled by log2e/8
  u16* Kh  = (u16*)(ws + 26 * MB);   // [16][4096][64]
  u16* Vt  = (u16*)(ws + 34 * MB);   // [16][64][4096]
  float* Op = (float*)(ws + 50 * MB);  // [2][16][4096][64] f32 partials
  float* Lw = (float*)(ws + 84 * MB);  // [2][16][4096] f32 row sums

  cvt_w<<<dim3(1024), dim3(256), 0, stream>>>(Wq, Wk, Wv, Wo, wqb);

  const float qscale = 0.125f * 1.44269504088896340736f;  // (1/sqrt(64)) * log2(e)
  gemm_qkv<<<dim3(128, 4, 3), dim3(256), 0, stream>>>(q, kv, wqb, wkb, wvb,
                                                      bq, bk, bv, Qh, Kh, Vt, qscale);

  attn_split<<<dim3(1024), dim3(256), 0, stream>>>(Qh, Kh, Vt, Op, Lw);

  gemm_out<<<dim3(128, 4), dim3(256), 0, stream>>>(Op, Lw, wob, bo, (float*)d_out);
}